// Round 12
// baseline (151.096 us; speedup 1.0000x reference)
//
#include <hip/hip_runtime.h>
#include <math.h>

#define O_CH 32
#define I_CH 3
#define IH 512
#define IW 512
#define OH 510
#define OW 510
#define N_IMG 16
#define WSTRIDE 32       // weight row stride in d_ws

typedef float v2f __attribute__((ext_vector_type(2)));
typedef float v4f __attribute__((ext_vector_type(4)));

__global__ __launch_bounds__(256) void gabor_weights_kernel(
    const float* __restrict__ freq, const float* __restrict__ theta,
    const float* __restrict__ psi, const float* __restrict__ sigma,
    float* __restrict__ wp) {
  int idx = blockIdx.x * 256 + threadIdx.x;
  if (idx >= O_CH * I_CH * 9) return;
  int o = idx / 27;
  int rem = idx % 27;          // rem = c*9 + kh*3 + kw
  int kh = (rem / 3) % 3;
  int kw = rem % 3;
  // linspace(-ceil(3/2)+1, ceil(3/2), 3) = {-1, 0.5, 2}
  float x = (kw == 0) ? -1.0f : (kw == 1 ? 0.5f : 2.0f);
  float y = (kh == 0) ? -1.0f : (kh == 1 ? 0.5f : 2.0f);
  int pi = o * I_CH + rem / 9; // (O,I) parameter index
  float th = theta[pi], f = freq[pi], p = psi[pi], s = sigma[pi];
  float ct = cosf(th), st = sinf(th);
  float rotx = x * ct + y * st;
  float roty = -x * st + y * ct;
  float se = s + 0.001f;
  float g = expf(-0.5f * (rotx * rotx + roty * roty) / (se * se));
  g *= cosf(f * rotx + p);
  g /= (2.0f * 3.14f * s * s);   // reference uses PI = 3.14 exactly
  wp[o * WSTRIDE + rem] = g;
}

// R9 structure (best: 132us) + store-phase decorrelation. Lane owns 16 px:
// rows (y,y+1) x cols {x0..x0+3} U {+256}; v_pk_fma_f32 pair axis = (L,R)
// halves (mov-free). NEW: each wave STAGGERS its o-loop start by
// ostart = (nid&1)<<4 | wave<<2 — co-resident same-SIMD waves (same wave id,
// adjacent nid) are 16 o-iters out of phase, so one wave FMAs while the
// other drains its store burst (compute emits ~23 TB/s instantaneous vs
// ~7 TB/s HBM -> stores must throttle; phase-aligned waves idled the SIMD).
// Iteration order doesn't change results. No min-waves clause (R5/R7 law).
__global__ __launch_bounds__(256) void gabor_conv_kernel(
    const float* __restrict__ in, const float* __restrict__ wgp,
    float* __restrict__ out) {
  __shared__ float sW[O_CH][28];   // 27 weights + pad, 7x float4 per o

  const int tid = threadIdx.x;
  for (int i = tid; i < O_CH * 28; i += 256) {
    int o = i / 28, j = i % 28;
    sW[o][j] = (j < 27) ? wgp[o * WSTRIDE + j] : 0.0f;
  }
  __syncthreads();

  const int wave = tid >> 6;   // 0..3
  const int lane = tid & 63;

  // bijective chunked XCD swizzle: 1024 blocks, 128 per XCD (= 2 images)
  const int bid = blockIdx.x;
  const int nid = (bid & 7) * 128 + (bid >> 3);
  const int n = nid >> 6;                  // image 0..15
  const int y = (nid & 63) * 8 + wave * 2; // even top row of this wave's pair
  if (y + 1 >= OH) return;                 // only tail-block wave 3 (y=510)

  const int x0 = lane * 4;                 // L px x0..x0+3; R px +256
  const float* inN = in + (size_t)n * (I_CH * IH * IW);

  // Window as (L,R) column pairs: 3 ch x 4 rows x 6 cols = 72 v2f
  v2f P[I_CH][4][6];
#pragma unroll
  for (int c = 0; c < I_CH; ++c) {
#pragma unroll
    for (int rw = 0; rw < 4; ++rw) {
      const float* rowp = inN + ((size_t)c * IH + y + rw) * IW;
      v4f LA = *(const v4f*)&rowp[x0];          // cols x0..x0+3 (16B aligned)
      v2f LB = *(const v2f*)&rowp[x0 + 4];      // cols x0+4,x0+5
      v4f RA = *(const v4f*)&rowp[x0 + 256];    // cols x0+256..+259
      int xc = x0 + 260; if (xc > IW - 2) xc = IW - 2;  // lane63: 512 -> 510
      v2f RB = *(const v2f*)&rowp[xc];
      P[c][rw][0] = (v2f){LA.x, RA.x};
      P[c][rw][1] = (v2f){LA.y, RA.y};
      P[c][rw][2] = (v2f){LA.z, RA.z};
      P[c][rw][3] = (v2f){LA.w, RA.w};
      P[c][rw][4] = (v2f){LB.x, RB.x};
      P[c][rw][5] = (v2f){LB.y, RB.y};
    }
  }

  const bool full = (lane != 63);   // lane63 R px 510,511 are OOB
  float* outBase = out + (((size_t)n * O_CH * OH) + y) * OW + x0;
  const int ostart = ((nid & 1) << 4) | (wave << 2);   // phase stagger

#pragma unroll 2
  for (int oi = 0; oi < O_CH; ++oi) {
    const int o = (oi + ostart) & 31;
    float wq[28];
#pragma unroll
    for (int k = 0; k < 7; ++k) {            // 7 broadcast ds_read_b128
      v4f t = *(const v4f*)&sW[o][k * 4];
      wq[4 * k + 0] = t.x; wq[4 * k + 1] = t.y;
      wq[4 * k + 2] = t.z; wq[4 * k + 3] = t.w;
    }
    v2f a0[4], a1[4];
#pragma unroll
    for (int j = 0; j < 4; ++j) { a0[j] = (v2f){0.f, 0.f}; a1[j] = (v2f){0.f, 0.f}; }
#pragma unroll
    for (int c = 0; c < I_CH; ++c) {
#pragma unroll
      for (int kh = 0; kh < 3; ++kh) {
#pragma unroll
        for (int kw = 0; kw < 3; ++kw) {
          float w = wq[c * 9 + kh * 3 + kw];
          v2f wv = (v2f){w, w};
#pragma unroll
          for (int j = 0; j < 4; ++j) {      // 8 v_pk_fma_f32 per tap
            a0[j] = __builtin_elementwise_fma(P[c][kh + 0][kw + j], wv, a0[j]);
            a1[j] = __builtin_elementwise_fma(P[c][kh + 1][kw + j], wv, a1[j]);
          }
        }
      }
    }
    // unpack (L,R) pairs into row-contiguous quads
    v4f L0 = (v4f){a0[0].x, a0[1].x, a0[2].x, a0[3].x};
    v4f R0 = (v4f){a0[0].y, a0[1].y, a0[2].y, a0[3].y};
    v4f L1 = (v4f){a1[0].x, a1[1].x, a1[2].x, a1[3].x};
    v4f R1 = (v4f){a1[0].y, a1[1].y, a1[2].y, a1[3].y};
    float* op = outBase + (size_t)o * (OH * OW);
    // row y: ob%4==0 (y even) -> dwordx4; row y+1: ob%4==2 -> 8B float2
    *(v4f*)op            = L0;
    *(v2f*)(op + OW)     = (v2f){L1.x, L1.y};
    *(v2f*)(op + OW + 2) = (v2f){L1.z, L1.w};
    if (full) {
      *(v4f*)(op + 256)      = R0;
      *(v2f*)(op + OW + 256) = (v2f){R1.x, R1.y};
      *(v2f*)(op + OW + 258) = (v2f){R1.z, R1.w};
    } else {
      *(v2f*)(op + 256)      = (v2f){R0.x, R0.y};   // px 508,509
      *(v2f*)(op + OW + 256) = (v2f){R1.x, R1.y};
    }
  }
}

extern "C" void kernel_launch(void* const* d_in, const int* in_sizes, int n_in,
                              void* d_out, int out_size, void* d_ws, size_t ws_size,
                              hipStream_t stream) {
  const float* img   = (const float*)d_in[0];
  const float* freq  = (const float*)d_in[1];
  const float* theta = (const float*)d_in[2];
  const float* psi   = (const float*)d_in[3];
  const float* sigma = (const float*)d_in[4];
  float* outp = (float*)d_out;
  float* wgp = (float*)d_ws;  // 32x32 floats of scratch (Gabor weights)

  gabor_weights_kernel<<<dim3(4), dim3(256), 0, stream>>>(freq, theta, psi, sigma, wgp);

  dim3 grid(N_IMG * 64);   // 1024 blocks; block = 8 rows (4 waves x row-pair)
  gabor_conv_kernel<<<grid, dim3(256), 0, stream>>>(img, wgp, outp);
}

// Round 13
// 126.727 us; speedup vs baseline: 1.1923x; 1.1923x over previous
//
#include <hip/hip_runtime.h>
#include <math.h>

#define O_CH 32
#define I_CH 3
#define IH 512
#define IW 512
#define OH 510
#define OW 510
#define N_IMG 16

typedef float v2f __attribute__((ext_vector_type(2)));
typedef float v4f __attribute__((ext_vector_type(4)));

// Single fused kernel: each block computes the 864 Gabor weights directly
// into LDS (4 transcendental iterations per thread, ~300 cyc — amortized
// over the ~16k-cyc main loop), removing the separate weights kernel, its
// launch bubble, and the d_ws round-trip (R12 delta vs R9).
//
// Main structure = R9 (best, 132us): lane owns 16 px: rows (y,y+1) x cols
// {x0..x0+3} U {x0+256..+259}. v_pk_fma_f32 pair axis = (L,R) halves: tap
// inputs are natural (L,R) v2f pairs built once at load (no per-tap
// repacking), weights splat to both halves. 216 pk-FMA per o for 16 px.
// Sequential o-loop, phase-aligned waves (R11 proved staggering o across
// waves HURTS: spreads concurrent writes over many o-planes -> worse L2
// writeback locality). No min-waves launch_bounds (R5/R7: forcing occupancy
// spills the register window -> 7-20x fetch amplification).
// Even row y: 16B dwordx4 stores; odd row y+1: 8B pieces (L2 merges; R3
// proved nontemporal bypasses merging -> 2x WRITE_SIZE).
// XCD chunk swizzle: 1024 blocks, q=128 = exactly 2 images per XCD.
__global__ __launch_bounds__(256) void gabor_conv_kernel(
    const float* __restrict__ in,
    const float* __restrict__ freq, const float* __restrict__ theta,
    const float* __restrict__ psi, const float* __restrict__ sigma,
    float* __restrict__ out) {
  __shared__ float sW[O_CH][28];   // 27 weights + pad, 7x float4 per o

  const int tid = threadIdx.x;
  // Compute all O*I*9 = 864 weights in-block (exact reference math, PI=3.14)
  for (int i = tid; i < O_CH * I_CH * 9; i += 256) {
    int o = i / 27;
    int rem = i % 27;            // rem = c*9 + kh*3 + kw
    int kh = (rem / 3) % 3;
    int kw = rem % 3;
    // linspace(-ceil(3/2)+1, ceil(3/2), 3) = {-1, 0.5, 2}
    float x = (kw == 0) ? -1.0f : (kw == 1 ? 0.5f : 2.0f);
    float y = (kh == 0) ? -1.0f : (kh == 1 ? 0.5f : 2.0f);
    int pi = o * I_CH + rem / 9; // (O,I) parameter index
    float th = theta[pi], f = freq[pi], p = psi[pi], s = sigma[pi];
    float ct = cosf(th), st = sinf(th);
    float rotx = x * ct + y * st;
    float roty = -x * st + y * ct;
    float se = s + 0.001f;
    float g = expf(-0.5f * (rotx * rotx + roty * roty) / (se * se));
    g *= cosf(f * rotx + p);
    g /= (2.0f * 3.14f * s * s);   // reference uses PI = 3.14 exactly
    sW[o][rem] = g;
  }
  if (tid < O_CH) sW[tid][27] = 0.0f;   // pad (read by b128, never used)
  __syncthreads();

  const int wave = tid >> 6;   // 0..3
  const int lane = tid & 63;

  // bijective chunked XCD swizzle: 1024 blocks, 128 per XCD (= 2 images)
  const int bid = blockIdx.x;
  const int nid = (bid & 7) * 128 + (bid >> 3);
  const int n = nid >> 6;                  // image 0..15
  const int y = (nid & 63) * 8 + wave * 2; // even top row of this wave's pair
  if (y + 1 >= OH) return;                 // only tail-block wave 3 (y=510)

  const int x0 = lane * 4;                 // L px x0..x0+3; R px +256
  const float* inN = in + (size_t)n * (I_CH * IH * IW);

  // Window as (L,R) column pairs: 3 ch x 4 rows x 6 cols = 72 v2f
  v2f P[I_CH][4][6];
#pragma unroll
  for (int c = 0; c < I_CH; ++c) {
#pragma unroll
    for (int rw = 0; rw < 4; ++rw) {
      const float* rowp = inN + ((size_t)c * IH + y + rw) * IW;
      v4f LA = *(const v4f*)&rowp[x0];          // cols x0..x0+3 (16B aligned)
      v2f LB = *(const v2f*)&rowp[x0 + 4];      // cols x0+4,x0+5
      v4f RA = *(const v4f*)&rowp[x0 + 256];    // cols x0+256..+259
      int xc = x0 + 260; if (xc > IW - 2) xc = IW - 2;  // lane63: 512 -> 510
      v2f RB = *(const v2f*)&rowp[xc];
      P[c][rw][0] = (v2f){LA.x, RA.x};
      P[c][rw][1] = (v2f){LA.y, RA.y};
      P[c][rw][2] = (v2f){LA.z, RA.z};
      P[c][rw][3] = (v2f){LA.w, RA.w};
      P[c][rw][4] = (v2f){LB.x, RB.x};
      P[c][rw][5] = (v2f){LB.y, RB.y};
    }
  }

  const bool full = (lane != 63);   // lane63 R px 510,511 are OOB
  float* op = out + (((size_t)n * O_CH * OH) + y) * OW + x0;  // o=0, row y, L

#pragma unroll 2
  for (int o = 0; o < O_CH; ++o) {
    float wq[28];
#pragma unroll
    for (int k = 0; k < 7; ++k) {            // 7 broadcast ds_read_b128
      v4f t = *(const v4f*)&sW[o][k * 4];
      wq[4 * k + 0] = t.x; wq[4 * k + 1] = t.y;
      wq[4 * k + 2] = t.z; wq[4 * k + 3] = t.w;
    }
    v2f a0[4], a1[4];
#pragma unroll
    for (int j = 0; j < 4; ++j) { a0[j] = (v2f){0.f, 0.f}; a1[j] = (v2f){0.f, 0.f}; }
#pragma unroll
    for (int c = 0; c < I_CH; ++c) {
#pragma unroll
      for (int kh = 0; kh < 3; ++kh) {
#pragma unroll
        for (int kw = 0; kw < 3; ++kw) {
          float w = wq[c * 9 + kh * 3 + kw];
          v2f wv = (v2f){w, w};
#pragma unroll
          for (int j = 0; j < 4; ++j) {      // 8 v_pk_fma_f32 per tap
            a0[j] = __builtin_elementwise_fma(P[c][kh + 0][kw + j], wv, a0[j]);
            a1[j] = __builtin_elementwise_fma(P[c][kh + 1][kw + j], wv, a1[j]);
          }
        }
      }
    }
    // unpack (L,R) pairs into row-contiguous quads
    v4f L0 = (v4f){a0[0].x, a0[1].x, a0[2].x, a0[3].x};
    v4f R0 = (v4f){a0[0].y, a0[1].y, a0[2].y, a0[3].y};
    v4f L1 = (v4f){a1[0].x, a1[1].x, a1[2].x, a1[3].x};
    v4f R1 = (v4f){a1[0].y, a1[1].y, a1[2].y, a1[3].y};
    // row y: ob%4==0 (y even) -> dwordx4; row y+1: ob%4==2 -> 8B float2
    *(v4f*)op            = L0;
    *(v2f*)(op + OW)     = (v2f){L1.x, L1.y};
    *(v2f*)(op + OW + 2) = (v2f){L1.z, L1.w};
    if (full) {
      *(v4f*)(op + 256)      = R0;
      *(v2f*)(op + OW + 256) = (v2f){R1.x, R1.y};
      *(v2f*)(op + OW + 258) = (v2f){R1.z, R1.w};
    } else {
      *(v2f*)(op + 256)      = (v2f){R0.x, R0.y};   // px 508,509
      *(v2f*)(op + OW + 256) = (v2f){R1.x, R1.y};
    }
    op += (size_t)(OH * OW);
  }
}

extern "C" void kernel_launch(void* const* d_in, const int* in_sizes, int n_in,
                              void* d_out, int out_size, void* d_ws, size_t ws_size,
                              hipStream_t stream) {
  const float* img   = (const float*)d_in[0];
  const float* freq  = (const float*)d_in[1];
  const float* theta = (const float*)d_in[2];
  const float* psi   = (const float*)d_in[3];
  const float* sigma = (const float*)d_in[4];
  float* outp = (float*)d_out;

  dim3 grid(N_IMG * 64);   // 1024 blocks; block = 8 rows (4 waves x row-pair)
  gabor_conv_kernel<<<grid, dim3(256), 0, stream>>>(img, freq, theta, psi,
                                                    sigma, outp);
}

// Round 14
// 125.788 us; speedup vs baseline: 1.2012x; 1.0075x over previous
//
#include <hip/hip_runtime.h>
#include <math.h>

#define O_CH 32
#define I_CH 3
#define IH 512
#define IW 512
#define OH 510
#define OW 510
#define N_IMG 16

typedef float v2f __attribute__((ext_vector_type(2)));
typedef float v4f __attribute__((ext_vector_type(4)));

// 16B store with only 8B-guaranteed alignment: CDNA global_store_dwordx4
// needs only dword alignment; __builtin_memcpy lets clang emit one dwordx4
// instead of 2x dwordx2 (odd rows: (510y+x0)%4==2). -33% store instrs.
__device__ __forceinline__ void store16(float* p, v4f v) {
  __builtin_memcpy((void*)p, &v, 16);
}

// Single fused kernel (R12 structure = best, 126.7us):
// - weights computed in-block into LDS (no separate kernel / d_ws trip)
// - lane owns 16 px: rows (y,y+1) x cols {x0..x0+3} U {x0+256..+259};
//   v_pk_fma_f32 pair axis = (L,R) halves, mov-free tap pairs
// - sequential o-loop, phase-aligned waves (R11: staggering hurts L2)
// - no min-waves launch_bounds (R5/R7: forcing occupancy spills the window)
// - regular stores (R3: nontemporal doubles WRITE_SIZE)
// - NEW (R13): ALL row-stores are single dwordx4 via store16 — odd rows
//   were 2x dwordx2; store instrs per o drop 6 -> 4, vmcnt queue -33%.
// XCD chunk swizzle: 1024 blocks, q=128 = exactly 2 images per XCD.
__global__ __launch_bounds__(256) void gabor_conv_kernel(
    const float* __restrict__ in,
    const float* __restrict__ freq, const float* __restrict__ theta,
    const float* __restrict__ psi, const float* __restrict__ sigma,
    float* __restrict__ out) {
  __shared__ float sW[O_CH][28];   // 27 weights + pad, 7x float4 per o

  const int tid = threadIdx.x;
  // Compute all O*I*9 = 864 weights in-block (exact reference math, PI=3.14)
  for (int i = tid; i < O_CH * I_CH * 9; i += 256) {
    int o = i / 27;
    int rem = i % 27;            // rem = c*9 + kh*3 + kw
    int kh = (rem / 3) % 3;
    int kw = rem % 3;
    // linspace(-ceil(3/2)+1, ceil(3/2), 3) = {-1, 0.5, 2}
    float x = (kw == 0) ? -1.0f : (kw == 1 ? 0.5f : 2.0f);
    float y = (kh == 0) ? -1.0f : (kh == 1 ? 0.5f : 2.0f);
    int pi = o * I_CH + rem / 9; // (O,I) parameter index
    float th = theta[pi], f = freq[pi], p = psi[pi], s = sigma[pi];
    float ct = cosf(th), st = sinf(th);
    float rotx = x * ct + y * st;
    float roty = -x * st + y * ct;
    float se = s + 0.001f;
    float g = expf(-0.5f * (rotx * rotx + roty * roty) / (se * se));
    g *= cosf(f * rotx + p);
    g /= (2.0f * 3.14f * s * s);   // reference uses PI = 3.14 exactly
    sW[o][rem] = g;
  }
  if (tid < O_CH) sW[tid][27] = 0.0f;   // pad (read by b128, never used)
  __syncthreads();

  const int wave = tid >> 6;   // 0..3
  const int lane = tid & 63;

  // bijective chunked XCD swizzle: 1024 blocks, 128 per XCD (= 2 images)
  const int bid = blockIdx.x;
  const int nid = (bid & 7) * 128 + (bid >> 3);
  const int n = nid >> 6;                  // image 0..15
  const int y = (nid & 63) * 8 + wave * 2; // even top row of this wave's pair
  if (y + 1 >= OH) return;                 // only tail-block wave 3 (y=510)

  const int x0 = lane * 4;                 // L px x0..x0+3; R px +256
  const float* inN = in + (size_t)n * (I_CH * IH * IW);

  // Window as (L,R) column pairs: 3 ch x 4 rows x 6 cols = 72 v2f
  v2f P[I_CH][4][6];
#pragma unroll
  for (int c = 0; c < I_CH; ++c) {
#pragma unroll
    for (int rw = 0; rw < 4; ++rw) {
      const float* rowp = inN + ((size_t)c * IH + y + rw) * IW;
      v4f LA = *(const v4f*)&rowp[x0];          // cols x0..x0+3 (16B aligned)
      v2f LB = *(const v2f*)&rowp[x0 + 4];      // cols x0+4,x0+5
      v4f RA = *(const v4f*)&rowp[x0 + 256];    // cols x0+256..+259
      int xc = x0 + 260; if (xc > IW - 2) xc = IW - 2;  // lane63: 512 -> 510
      v2f RB = *(const v2f*)&rowp[xc];
      P[c][rw][0] = (v2f){LA.x, RA.x};
      P[c][rw][1] = (v2f){LA.y, RA.y};
      P[c][rw][2] = (v2f){LA.z, RA.z};
      P[c][rw][3] = (v2f){LA.w, RA.w};
      P[c][rw][4] = (v2f){LB.x, RB.x};
      P[c][rw][5] = (v2f){LB.y, RB.y};
    }
  }

  const bool full = (lane != 63);   // lane63 R px 510,511 are OOB
  float* op = out + (((size_t)n * O_CH * OH) + y) * OW + x0;  // o=0, row y, L

#pragma unroll 2
  for (int o = 0; o < O_CH; ++o) {
    float wq[28];
#pragma unroll
    for (int k = 0; k < 7; ++k) {            // 7 broadcast ds_read_b128
      v4f t = *(const v4f*)&sW[o][k * 4];
      wq[4 * k + 0] = t.x; wq[4 * k + 1] = t.y;
      wq[4 * k + 2] = t.z; wq[4 * k + 3] = t.w;
    }
    v2f a0[4], a1[4];
#pragma unroll
    for (int j = 0; j < 4; ++j) { a0[j] = (v2f){0.f, 0.f}; a1[j] = (v2f){0.f, 0.f}; }
#pragma unroll
    for (int c = 0; c < I_CH; ++c) {
#pragma unroll
      for (int kh = 0; kh < 3; ++kh) {
#pragma unroll
        for (int kw = 0; kw < 3; ++kw) {
          float w = wq[c * 9 + kh * 3 + kw];
          v2f wv = (v2f){w, w};
#pragma unroll
          for (int j = 0; j < 4; ++j) {      // 8 v_pk_fma_f32 per tap
            a0[j] = __builtin_elementwise_fma(P[c][kh + 0][kw + j], wv, a0[j]);
            a1[j] = __builtin_elementwise_fma(P[c][kh + 1][kw + j], wv, a1[j]);
          }
        }
      }
    }
    // unpack (L,R) pairs into row-contiguous quads
    v4f L0 = (v4f){a0[0].x, a0[1].x, a0[2].x, a0[3].x};
    v4f R0 = (v4f){a0[0].y, a0[1].y, a0[2].y, a0[3].y};
    v4f L1 = (v4f){a1[0].x, a1[1].x, a1[2].x, a1[3].x};
    v4f R1 = (v4f){a1[0].y, a1[1].y, a1[2].y, a1[3].y};
    // every row-store = one dwordx4 (odd rows align-8 via store16)
    store16(op, L0);
    store16(op + OW, L1);
    if (full) {
      store16(op + 256, R0);
      store16(op + OW + 256, R1);
    } else {
      *(v2f*)(op + 256)      = (v2f){R0.x, R0.y};   // px 508,509
      *(v2f*)(op + OW + 256) = (v2f){R1.x, R1.y};
    }
    op += (size_t)(OH * OW);
  }
}

extern "C" void kernel_launch(void* const* d_in, const int* in_sizes, int n_in,
                              void* d_out, int out_size, void* d_ws, size_t ws_size,
                              hipStream_t stream) {
  const float* img   = (const float*)d_in[0];
  const float* freq  = (const float*)d_in[1];
  const float* theta = (const float*)d_in[2];
  const float* psi   = (const float*)d_in[3];
  const float* sigma = (const float*)d_in[4];
  float* outp = (float*)d_out;

  dim3 grid(N_IMG * 64);   // 1024 blocks; block = 8 rows (4 waves x row-pair)
  gabor_conv_kernel<<<grid, dim3(256), 0, stream>>>(img, freq, theta, psi,
                                                    sigma, outp);
}